// Round 1
// baseline (811.289 us; speedup 1.0000x reference)
//
#include <hip/hip_runtime.h>
#include <math.h>

#define D 64
#define HD 192
#define NN 512
#define NT 4096
#define EPB 64
#define SH 196   // H row stride (floats): e-read bank step 4*196%32=16? no: Δte=4*SH -> see mapping e=te+16i, Δ=196*4B, %32banks = 4 -> 2-way (free)
#define SW 196   // W tile row stride

__device__ __forceinline__ float gelu_exact(float x) {
    return 0.5f * x * (1.0f + erff(x * 0.70710678118654752440f));
}

// ---------------- kernel S: per-edge MLP score + segment denom ----------------
// block = 256 threads, 64 edges/block.
// thread (te = tid&15, tj = tid>>4) computes edges e = te+16i (i<4), j = tj*12+u (u<12).
__global__ __launch_bounds__(256, 2)
void score_kernel(const float* __restrict__ nf, const float* __restrict__ adj,
                  const float* __restrict__ W1, const float* __restrict__ W2,
                  const int* __restrict__ eidx, int E,
                  float* __restrict__ attn, float* __restrict__ denom)
{
    __shared__ float Hs[EPB * SH];     // 50176 B, H row-major [e][192] padded
    __shared__ float Ws[16 * SW];      // 12544 B, W1 k-tile transposed [kk][j]; reused as sred
    __shared__ int   srcS[EPB], dstS[EPB];

    const int tid = threadIdx.x;
    const int te  = tid & 15;
    const int tj  = tid >> 4;
    const int e0  = blockIdx.x * EPB;

    if (tid < EPB) {
        srcS[tid] = eidx[e0 + tid];
        dstS[tid] = eidx[E + e0 + tid];
    }
    __syncthreads();

    // ---- stage H: [e][0:64]=nf[dst], [64:128]=nf[src], [128:192]=adj row ----
    #pragma unroll
    for (int it = 0; it < 12; ++it) {
        int idx = tid + it * 256;          // 3072 float4 chunks total
        int e = idx / 48;
        int c = idx - e * 48;
        const float* srcp;
        if (c < 16) {
            srcp = nf + (size_t)dstS[e] * D + c * 4;
        } else if (c < 32) {
            srcp = nf + (size_t)srcS[e] * D + (c - 16) * 4;
        } else {
            int s = srcS[e], d = dstS[e];
            size_t base = ((size_t)s * NN + (size_t)(d & (NN - 1))) * D;
            srcp = adj + base + (c - 32) * 4;
        }
        float4 v = *(const float4*)srcp;
        *(float4*)(&Hs[e * SH + c * 4]) = v;
    }

    float acc[4][12];
    #pragma unroll
    for (int i = 0; i < 4; ++i)
        #pragma unroll
        for (int u = 0; u < 12; ++u) acc[i][u] = 0.f;

    // ---- GEMM: acc[i][u] = sum_k H[te+16i][k] * W1[tj*12+u][k] ----
    for (int kt = 0; kt < HD; kt += 16) {
        __syncthreads();
        {   // stage Wt[kk][j] = W1[j][kt+kk]
            int kk = tid & 15;
            int jb = tid >> 4;
            #pragma unroll
            for (int i = 0; i < 12; ++i) {
                int j = jb + 16 * i;
                Ws[kk * SW + j] = W1[(size_t)j * HD + kt + kk];
            }
        }
        __syncthreads();
        #pragma unroll
        for (int kk = 0; kk < 16; ++kk) {
            int k = kt + kk;
            float aa[4];
            aa[0] = Hs[(te +  0) * SH + k];
            aa[1] = Hs[(te + 16) * SH + k];
            aa[2] = Hs[(te + 32) * SH + k];
            aa[3] = Hs[(te + 48) * SH + k];
            const float4 b0 = *(const float4*)&Ws[kk * SW + tj * 12 + 0];
            const float4 b1 = *(const float4*)&Ws[kk * SW + tj * 12 + 4];
            const float4 b2 = *(const float4*)&Ws[kk * SW + tj * 12 + 8];
            const float bb[12] = {b0.x,b0.y,b0.z,b0.w, b1.x,b1.y,b1.z,b1.w, b2.x,b2.y,b2.z,b2.w};
            #pragma unroll
            for (int i = 0; i < 4; ++i)
                #pragma unroll
                for (int u = 0; u < 12; ++u)
                    acc[i][u] = fmaf(aa[i], bb[u], acc[i][u]);
        }
    }

    // ---- epilogue: gelu -> dot W2 -> cross-thread reduce -> exp/mask ----
    float part[4] = {0.f, 0.f, 0.f, 0.f};
    #pragma unroll
    for (int u = 0; u < 12; ++u) {
        float w2 = W2[tj * 12 + u];
        #pragma unroll
        for (int i = 0; i < 4; ++i)
            part[i] += gelu_exact(acc[i][u]) * w2;
    }

    __syncthreads();                 // all Ws reads done -> safe to reuse as sred
    float* sred = Ws;                // [16 tj][64 e]
    #pragma unroll
    for (int i = 0; i < 4; ++i)
        sred[tj * EPB + te + 16 * i] = part[i];
    __syncthreads();

    if (tid < EPB) {
        float s = 0.f;
        #pragma unroll
        for (int t = 0; t < 16; ++t) s += sred[t * EPB + tid];
        float score = expf(s);
        int sg = srcS[tid], dg = dstS[tid];
        int diff = sg - dg; if (diff < 0) diff = -diff;
        float a = (diff > 1) ? score : 0.f;
        attn[e0 + tid] = a;
        if (a != 0.f) atomicAdd(&denom[dg], a);
    }
}

// ---------------- kernel O: out[dst] += edges * attn/denom ----------------
// one wave per edge, lane = feature d
__global__ __launch_bounds__(256)
void out_kernel(const float* __restrict__ adj, const int* __restrict__ eidx, int E,
                const float* __restrict__ attn, const float* __restrict__ denom,
                float* __restrict__ out)
{
    int wv   = threadIdx.x >> 6;
    int lane = threadIdx.x & 63;
    int e = blockIdx.x * 4 + wv;
    if (e >= E) return;
    float a = attn[e];
    if (a == 0.f) return;
    int s = eidx[e], d = eidx[E + e];
    float den = denom[d];
    float w = a / ((den == 0.f) ? 1.f : den);
    size_t base = ((size_t)s * NN + (size_t)(d & (NN - 1))) * D;
    atomicAdd(&out[(size_t)d * D + lane], adj[base + lane] * w);
}

extern "C" void kernel_launch(void* const* d_in, const int* in_sizes, int n_in,
                              void* d_out, int out_size, void* d_ws, size_t ws_size,
                              hipStream_t stream)
{
    const float* nf   = (const float*)d_in[0];
    const float* adj  = (const float*)d_in[1];
    const float* W1   = (const float*)d_in[2];
    const float* W2   = (const float*)d_in[3];
    const int*   eidx = (const int*)d_in[4];
    const int E = in_sizes[4] / 2;

    float* out   = (float*)d_out;
    float* attn  = (float*)d_ws;          // E floats
    float* denom = attn + E;              // NT floats

    hipMemsetAsync(denom, 0, NT * sizeof(float), stream);
    hipMemsetAsync(d_out, 0, (size_t)out_size * sizeof(float), stream);

    score_kernel<<<E / EPB, 256, 0, stream>>>(nf, adj, W1, W2, eidx, E, attn, denom);
    out_kernel<<<(E + 3) / 4, 256, 0, stream>>>(adj, eidx, E, attn, denom, out);
}